// Round 3
// baseline (544.201 us; speedup 1.0000x reference)
//
#include <hip/hip_runtime.h>

// Problem constants
#define NB   4      // batch
#define NN   4      // contexts per pixel
#define CCh  256    // Cc
#define CFh  512    // Cf
#define HH   128
#define WW   128
#define PLO  4096   // 64*64 low-res pixels
#define PHI  16384  // 128*128 hi-res pixels

typedef __bf16 bf16;
typedef __bf16 bf16x8 __attribute__((ext_vector_type(8)));
typedef float  f32x4  __attribute__((ext_vector_type(4)));

__device__ __forceinline__ void gll16(const void* g, void* lds) {
    __builtin_amdgcn_global_load_lds(
        (const __attribute__((address_space(1))) void*)g,
        (__attribute__((address_space(3))) void*)lds, 16, 0, 0);
}

__device__ __forceinline__ float bflo(unsigned u) { return __uint_as_float(u << 16); }
__device__ __forceinline__ float bfhi(unsigned u) { return __uint_as_float(u & 0xffff0000u); }

// ---------------------------------------------------------------------------
// fused prep kernel, block-specialized:
//  bid [0,512):      M_qk[c][f] = sum_o Wc_w[o][c]*Wf_w[o][f] (bf16), d_qk
//  bid [512,8704):   transpose ms [B][512][4096] fp32 -> ms_t [B][4096][512] bf16
//  bid [8704,13312): pack Wv_w [256][512][3][3] -> Wv_p [9][256][512] bf16; zerob
__global__ __launch_bounds__(256) void prep_all(
    const float* __restrict__ Wc_w, const float* __restrict__ Wf_w,
    const float* __restrict__ Wf_b, const float* __restrict__ ms,
    const float* __restrict__ Wv_w,
    bf16* __restrict__ M_qk, float* __restrict__ d_qk,
    bf16* __restrict__ ms_t, bf16* __restrict__ Wv_p, bf16* __restrict__ zerob) {
    __shared__ float tile[32][33];
    const int bid = blockIdx.x, tx = threadIdx.x;
    if (bid < 512) {
        int c = bid >> 1;
        int f = (bid & 1) * 256 + tx;
        float s = 0.f;
#pragma unroll 8
        for (int o = 0; o < CCh; ++o)
            s += Wc_w[o * CCh + c] * Wf_w[o * CFh + f];
        M_qk[c * CFh + f] = (bf16)s;
        if ((bid & 1) == 0 && tx == 0) {
            float d = 0.f;
            for (int o = 0; o < CCh; ++o) d += Wc_w[o * CCh + c] * Wf_b[o];
            d_qk[c] = d;
        }
    } else if (bid < 8704) {
        int id = bid - 512;
        int b = id >> 11, f0 = ((id >> 7) & 15) * 32, p0 = (id & 127) * 32;
        int r = tx >> 5, cc = tx & 31;
        const float* src = ms + (size_t)b * CFh * PLO;
#pragma unroll
        for (int q = 0; q < 4; ++q) {
            int fl = q * 8 + r;
            tile[fl][cc] = src[(size_t)(f0 + fl) * PLO + p0 + cc];
        }
        __syncthreads();
        bf16* dst = ms_t + (size_t)b * PLO * CFh;
#pragma unroll
        for (int q = 0; q < 4; ++q) {
            int pl = q * 8 + r;
            dst[(size_t)(p0 + pl) * CFh + f0 + cc] = (bf16)tile[cc][pl];
        }
    } else {
        int tid = (bid - 8704) * 256 + tx;   // t-major: (t*256 + c)*512 + f
        int t = tid / (CCh * CFh);
        int rem = tid % (CCh * CFh);
        int c = rem / CFh, f = rem % CFh;
        Wv_p[tid] = (bf16)Wv_w[(size_t)(c * CFh + f) * 9 + t];
        if (tid < 1024) zerob[tid] = (bf16)0.f;
    }
}

// ---------------------------------------------------------------------------
// GEMM: M=channels(128-tile), N=pixels(128-tile), BK=32, 256 thr = 4 waves.
// grid (32, 2, 16): z<12 -> conv tap-group tg=z%3 (rows dy=tg-1), b=z/3,
//   writes bf16 partials (no bias) to vpart[tg][b][256][4096].
// z>=12 -> qk (1 tap), b=z-12, writes bf16 (+d_qk bias) to qk_out.
__global__ __launch_bounds__(256) void gemm_kernel(
    const bf16* __restrict__ Wv_p,   // [9][256][512]
    const bf16* __restrict__ M_qk,   // [256][512]
    const bf16* __restrict__ ms_t,   // [B][4096][512]
    const float* __restrict__ d_qk,
    const bf16* __restrict__ zerob,
    bf16* __restrict__ vpart, bf16* __restrict__ qk_out) {
    __shared__ __align__(16) bf16 Alds[128 * 32];  // [c][f]
    __shared__ __align__(16) bf16 Blds[128 * 32];  // [p][f]

    const int tx = threadIdx.x;
    const int wave = tx >> 6, lane = tx & 63;
    const int ptile = blockIdx.x, ctile = blockIdx.y;
    const int z = blockIdx.z;
    const int mode = (z >= 12);                 // 0=conv partial, 1=qk
    const int b = mode ? (z - 12) : (z / 3);
    const int tg = mode ? 0 : (z % 3);
    const int t0 = tg * 3;
    const int ntaps = mode ? 1 : 3;

    const bf16* Wbase = mode ? M_qk : (Wv_p + (size_t)t0 * CCh * CFh);
    const bf16* msb = ms_t + (size_t)b * PLO * CFh;

    int idx0 = wave * 2048 + lane * 16;
    int idx1 = idx0 + 1024;
    int rA0 = idx0 >> 6, fq0 = (idx0 >> 4) & 3;
    int rA1 = idx1 >> 6, fq1 = (idx1 >> 4) & 3;
    const size_t aoff0 = (size_t)(ctile * 128 + rA0) * CFh + fq0 * 8;
    const size_t aoff1 = (size_t)(ctile * 128 + rA1) * CFh + fq1 * 8;
    char* ldsA0 = (char*)Alds + wave * 2048;
    char* ldsA1 = ldsA0 + 1024;
    char* ldsB0 = (char*)Blds + wave * 2048;
    char* ldsB1 = ldsB0 + 1024;

    const int p0 = ptile * 128 + rA0, p1 = ptile * 128 + rA1;
    const int i0 = p0 >> 6, j0 = p0 & 63;
    const int i1 = p1 >> 6, j1 = p1 & 63;

    f32x4 acc[4][4];
#pragma unroll
    for (int mi = 0; mi < 4; ++mi)
#pragma unroll
        for (int ni = 0; ni < 4; ++ni) acc[mi][ni] = f32x4{0.f, 0.f, 0.f, 0.f};

    const int wm = wave >> 1, wn = wave & 1;
    const int quad = lane >> 4, l15 = lane & 15;

    for (int t = 0; t < ntaps; ++t) {
        const int dy = mode ? 0 : ((t0 + t) / 3 - 1);
        const int dx = mode ? 0 : ((t0 + t) % 3 - 1);
        const bf16* Wt = Wbase + (size_t)t * CCh * CFh;
        int si0 = i0 + dy, sj0 = j0 + dx, si1 = i1 + dy, sj1 = j1 + dx;
        bool ok0 = (unsigned)si0 < 64u && (unsigned)sj0 < 64u;
        bool ok1 = (unsigned)si1 < 64u && (unsigned)sj1 < 64u;
        const bf16* bsrc0 = ok0 ? msb + (size_t)(si0 * 64 + sj0) * CFh + fq0 * 8 : zerob;
        const bf16* bsrc1 = ok1 ? msb + (size_t)(si1 * 64 + sj1) * CFh + fq1 * 8 : zerob;

        for (int fc = 0; fc < CFh / 32; ++fc) {
            const int f0 = fc * 32;
            __syncthreads();
            gll16(Wt + aoff0 + f0, ldsA0);
            gll16(Wt + aoff1 + f0, ldsA1);
            gll16(bsrc0 + f0, ldsB0);
            gll16(bsrc1 + f0, ldsB1);
            __syncthreads();

            bf16x8 af[4], bfr[4];
#pragma unroll
            for (int mi = 0; mi < 4; ++mi)
                af[mi] = *(const bf16x8*)&Alds[(wm * 64 + mi * 16 + l15) * 32 + quad * 8];
#pragma unroll
            for (int ni = 0; ni < 4; ++ni)
                bfr[ni] = *(const bf16x8*)&Blds[(wn * 64 + ni * 16 + l15) * 32 + quad * 8];
#pragma unroll
            for (int mi = 0; mi < 4; ++mi)
#pragma unroll
                for (int ni = 0; ni < 4; ++ni)
                    acc[mi][ni] = __builtin_amdgcn_mfma_f32_16x16x32_bf16(
                        af[mi], bfr[ni], acc[mi][ni], 0, 0, 0);
        }
    }

    // C/D layout: col = lane&15 (pixel), row = quad*4 + r (channel)
    if (mode) {
        bf16* obase = qk_out + (size_t)b * CCh * PLO;
#pragma unroll
        for (int mi = 0; mi < 4; ++mi) {
            int cb = ctile * 128 + wm * 64 + mi * 16 + quad * 4;
#pragma unroll
            for (int ni = 0; ni < 4; ++ni) {
                int p = ptile * 128 + wn * 64 + ni * 16 + l15;
                bf16* op = obase + (size_t)cb * PLO + p;
#pragma unroll
                for (int r = 0; r < 4; ++r)
                    op[(size_t)r * PLO] = (bf16)(acc[mi][ni][r] + d_qk[cb + r]);
            }
        }
    } else {
        bf16* obase = vpart + (size_t)(tg * NB + b) * CCh * PLO;
#pragma unroll
        for (int mi = 0; mi < 4; ++mi) {
            int cb = ctile * 128 + wm * 64 + mi * 16 + quad * 4;
#pragma unroll
            for (int ni = 0; ni < 4; ++ni) {
                int p = ptile * 128 + wn * 64 + ni * 16 + l15;
                bf16* op = obase + (size_t)cb * PLO + p;
#pragma unroll
                for (int r = 0; r < 4; ++r)
                    op[(size_t)r * PLO] = (bf16)acc[mi][ni][r];
            }
        }
    }
}

// ---------------------------------------------------------------------------
// attention, single ctx pass: block = 256 thr = 16 px (4 groups of 4) x 64
// channel-chunks of 4. Thread holds ctx 4px x 4c x 4n in VGPRs (64 regs).
// Score reduce: shfl-xor over lane bits 2..5, then 4-wave LDS stage.
__global__ __launch_bounds__(256, 3) void attn_kernel(
    const float* __restrict__ ctx,   // [4][4][256][128][128]
    const bf16* __restrict__ qk,     // [4][256][4096]
    const bf16* __restrict__ vpart,  // [3][4][256][4096] conv partials
    const float* __restrict__ Wv_b,  // [256]
    float* __restrict__ out) {       // [4][256][128][128]
    __shared__ f32x4 swred[4][4][4];  // [wave][pq][n]
    const int tx = threadIdx.x;
    const int pq = tx & 3;             // 4-pixel group
    const int cz = tx >> 2;            // channel chunk 0..63
    const int lane = tx & 63, wv = tx >> 6;
    const int c0 = cz * 4;

    const int pbase = blockIdx.x << 4;
    const int b = pbase >> 14;
    const int rem = pbase & 16383;
    const int hh = rem >> 7;
    const int w0 = rem & 127;
    const int wq = w0 + pq * 4;
    const int i = hh >> 1, j0 = wq >> 1;   // j0 even

    const size_t NSTR = (size_t)CCh * PHI;
    const float* cbase = ctx + ((size_t)b * NN * CCh + c0) * PHI + (size_t)hh * WW + wq;
    const bf16* qkb = qk + ((size_t)b * CCh + c0) * PLO + i * 64 + j0;
    const bf16* vb  = vpart + ((size_t)b * CCh + c0) * PLO + i * 64 + j0;

    f32x4 vals[4][4];
    f32x4 s[4];
#pragma unroll
    for (int n = 0; n < 4; ++n) s[n] = f32x4{0.f, 0.f, 0.f, 0.f};

#pragma unroll
    for (int cj = 0; cj < 4; ++cj) {
        unsigned qw = *(const unsigned*)(qkb + (size_t)cj * PLO);
        float qa = bflo(qw), qb = bfhi(qw);
        f32x4 qv = {qa, qa, qb, qb};
#pragma unroll
        for (int n = 0; n < 4; ++n) {
            vals[n][cj] = *(const f32x4*)(cbase + n * NSTR + (size_t)cj * PHI);
            s[n] += vals[n][cj] * qv;
        }
    }
    // butterfly over lane bits 2..5 (the in-wave channel-chunk bits)
#pragma unroll
    for (int n = 0; n < 4; ++n) {
#pragma unroll
        for (int m = 4; m <= 32; m <<= 1) {
            f32x4 t;
            t[0] = __shfl_xor(s[n][0], m);
            t[1] = __shfl_xor(s[n][1], m);
            t[2] = __shfl_xor(s[n][2], m);
            t[3] = __shfl_xor(s[n][3], m);
            s[n] += t;
        }
    }
    // lanes 0..15: (pq=lane&3, n=lane>>2) publish per-wave partials
    int npub = (lane >> 2) & 3;
    f32x4 sq = (npub == 0) ? s[0] : (npub == 1) ? s[1] : (npub == 2) ? s[2] : s[3];
    if (lane < 16) swred[wv][lane & 3][npub] = sq;
    __syncthreads();

    f32x4 t4[4];
#pragma unroll
    for (int n = 0; n < 4; ++n)
        t4[n] = swred[0][pq][n] + swred[1][pq][n] + swred[2][pq][n] + swred[3][pq][n];
    f32x4 mx;
#pragma unroll
    for (int k = 0; k < 4; ++k)
        mx[k] = fmaxf(fmaxf(t4[0][k], t4[1][k]), fmaxf(t4[2][k], t4[3][k]));
    f32x4 e[4];
#pragma unroll
    for (int n = 0; n < 4; ++n)
#pragma unroll
        for (int k = 0; k < 4; ++k) e[n][k] = __expf(t4[n][k] - mx[k]);
    f32x4 ssum = e[0] + e[1] + e[2] + e[3];
    f32x4 a4[4];
#pragma unroll
    for (int n = 0; n < 4; ++n)
#pragma unroll
        for (int k = 0; k < 4; ++k) a4[n][k] = e[n][k] / ssum[k];

    const size_t TGS = (size_t)NB * CCh * PLO;
    f32x4 bcv = *(const f32x4*)(Wv_b + c0);
    float* outp = out + ((size_t)b * CCh + c0) * PHI + (size_t)hh * WW + wq;
#pragma unroll
    for (int cj = 0; cj < 4; ++cj) {
        unsigned u0 = *(const unsigned*)(vb + (size_t)cj * PLO);
        unsigned u1 = *(const unsigned*)(vb + TGS + (size_t)cj * PLO);
        unsigned u2 = *(const unsigned*)(vb + 2 * TGS + (size_t)cj * PLO);
        float va  = bflo(u0) + bflo(u1) + bflo(u2) + bcv[cj];
        float vbb = bfhi(u0) + bfhi(u1) + bfhi(u2) + bcv[cj];
        f32x4 o = vals[0][cj] * a4[0] + vals[1][cj] * a4[1] +
                  vals[2][cj] * a4[2] + vals[3][cj] * a4[3] +
                  f32x4{va, va, vbb, vbb};
        *(f32x4*)(outp + (size_t)cj * PHI) = o;
    }
}

// ---------------------------------------------------------------------------
extern "C" void kernel_launch(void* const* d_in, const int* in_sizes, int n_in,
                              void* d_out, int out_size, void* d_ws, size_t ws_size,
                              hipStream_t stream) {
    const float* ctx  = (const float*)d_in[0];
    const float* ms   = (const float*)d_in[1];
    const float* Wc_w = (const float*)d_in[2];
    // d_in[3] = Wc_b: constant across n at each pixel -> cancels in softmax.
    const float* Wf_w = (const float*)d_in[4];
    const float* Wf_b = (const float*)d_in[5];
    const float* Wv_w = (const float*)d_in[6];
    const float* Wv_b = (const float*)d_in[7];
    float* out = (float*)d_out;

    char* ws = (char*)d_ws;
    bf16*  ms_t  = (bf16*)ws;                     // 16,777,216 B
    bf16*  Wv_p  = (bf16*)(ws + 16777216);        //  2,359,296 B
    bf16*  M_qk  = (bf16*)(ws + 19136512);        //    262,144 B
    float* d_qk  = (float*)(ws + 19398656);       //      1,024 B
    bf16*  zerob = (bf16*)(ws + 19399680);        //      2,048 B
    bf16*  qk    = (bf16*)(ws + 19401728);        //  8,388,608 B
    bf16*  vpart = (bf16*)(ws + 27790336);        // 25,165,824 B (total ~52.9 MB)

    prep_all<<<dim3(13312), 256, 0, stream>>>(Wc_w, Wf_w, Wf_b, ms, Wv_w,
                                              M_qk, d_qk, ms_t, Wv_p, zerob);
    gemm_kernel<<<dim3(32, 2, 16), 256, 0, stream>>>(Wv_p, M_qk, ms_t, d_qk,
                                                     zerob, vpart, qk);
    attn_kernel<<<dim3(4096), 256, 0, stream>>>(ctx, qk, vpart, Wv_b, out);
}